// Round 6
// baseline (123.177 us; speedup 1.0000x reference)
//
#include <hip/hip_runtime.h>
#include <hip/hip_bf16.h>
#include <math.h>

// S5 SSM layer. B_SZ=16, L=1024, H=256, P=256.
// 3 dispatches:
//   k_prep     : W1T, W2T, PW (lambda-power table)
//   k_g1scan   : per-chunk GEMM1 (u@B_bar^T) -> LDS -> local scan -> XS(x_local) + CEND
//   k_gemm2fix : per-block carry recompute from CEND + fixup-in-staging GEMM2 + D*u
#define BB     16
#define LSEQ   1024
#define HH     256
#define PP     256
#define MROWS  (BB*LSEQ)     // 16384
#define LC     32
#define NC     (LSEQ/LC)     // 32
#define NCHUNK (BB*NC)       // 512

// workspace byte offsets
#define OFF_W1T  0u          // [512][256] bf16: row 2p=Re(B_bar[p][.]), 2p+1=Im
#define OFF_W2T  262144u     // [256][512] bf16: row h, k=2p -> 2*C_re, 2p+1 -> -2*C_im
#define OFF_PW   524288u     // [33][256] float2: lambda_bar^t
#define OFF_CEND 655360u     // [512][256] float2 chunk-end local states
#define OFF_XS   1703936u    // [16384][512] bf16 x_local (col 2p=re, 2p+1=im)
// total ~18.5 MB

#define XSTRIDE 520          // bf16 elems per LDS X row in g1scan (512 + 8 pad)

typedef __attribute__((ext_vector_type(8))) short short8;
typedef __attribute__((ext_vector_type(4))) float floatx4;

__device__ __forceinline__ float bf2f(unsigned hs) {
    union { unsigned u; float f; } v; v.u = hs << 16; return v.f;
}
__device__ __forceinline__ unsigned short f2bs(float f) {
    __hip_bfloat16 h = __float2bfloat16(f);
    union { __hip_bfloat16 h; unsigned short s; } v; v.h = h; return v.s;
}
__device__ __forceinline__ unsigned packbf(float r, float i) {
    return (unsigned)f2bs(r) | ((unsigned)f2bs(i) << 16);
}
__device__ __forceinline__ void async16(const void* g, void* l) {
    __builtin_amdgcn_global_load_lds(
        (const __attribute__((address_space(1))) unsigned*)g,
        (__attribute__((address_space(3))) unsigned*)l, 16, 0, 0);
}
__device__ __forceinline__ float2 lam_pow(float lr, float li, float dtt) {
    float m = expf(lr * dtt);
    return make_float2(m * cosf(li * dtt), m * sinf(li * dtt));
}

// ---------------- prep: W1T (blocks 0..255, + PW) and W2T (blocks 256..511) ----------------
__global__ void k_prep(const float* __restrict__ Bm, const float* __restrict__ Cm,
                       const float* __restrict__ Lr, const float* __restrict__ Li,
                       const float* __restrict__ ls, char* __restrict__ ws) {
    int blk = blockIdx.x, t = threadIdx.x;
    if (blk < 256) {
        int p = blk, h = t;
        float lr = Lr[p], li = Li[p];
        float dt = expf(ls[p]);
        float2 lam = lam_pow(lr, li, dt);
        float den = lr * lr + li * li;
        float nr = lam.x - 1.0f, ni = lam.y;
        float cr = (nr * lr + ni * li) / den;       // (lam_bar-1)/Lambda
        float ci = (ni * lr - nr * li) / den;
        float br = Bm[(p * HH + h) * 2 + 0];
        float bi = Bm[(p * HH + h) * 2 + 1];
        unsigned short* w1 = (unsigned short*)(ws + OFF_W1T);
        w1[(2 * p) * 256 + h]     = f2bs(cr * br - ci * bi);
        w1[(2 * p + 1) * 256 + h] = f2bs(cr * bi + ci * br);
        if (t <= 32)   // lambda power table pw[t][p]
            ((float2*)(ws + OFF_PW))[t * 256 + p] = lam_pow(lr, li, dt * (float)t);
    } else {
        int h = blk - 256, p = t;
        float c_r = Cm[(h * PP + p) * 2 + 0];
        float c_i = Cm[(h * PP + p) * 2 + 1];
        ((unsigned*)(ws + OFF_W2T))[h * 256 + p] = packbf(2.0f * c_r, -2.0f * c_i);
    }
}

// ---------------- fused GEMM1 + local chunk scan (512 threads / 8 waves) ----------------
// One block per chunk: rows m0..m0+31, N=512, K=256. Each wave owns a 64-col slice.
__global__ __launch_bounds__(512, 4) void k_g1scan(
        const float* __restrict__ u, const float* __restrict__ Lr,
        const float* __restrict__ Li, const float* __restrict__ ls,
        char* __restrict__ ws) {
    __shared__ char smem[2048 + 33280];   // As 32x32 bf16 | Bs 512x32 bf16 UNION X 32x520 bf16
    unsigned*  As32 = (unsigned*)smem;
    char*      Bs   = smem + 2048;
    unsigned short* X = (unsigned short*)(smem + 2048);
    unsigned*  X32  = (unsigned*)(smem + 2048);
    const unsigned short* W1 = (const unsigned short*)(ws + OFF_W1T);
    const int tid = threadIdx.x, bc = blockIdx.x;
    const int wave = tid >> 6, lane = tid & 63;
    const int q = lane >> 4, rr = lane & 15;
    const int c4 = lane & 3, r4 = lane >> 2;
    const int m0 = bc * LC;

    floatx4 acc[2][4];
    #pragma unroll
    for (int i = 0; i < 2; ++i)
        #pragma unroll
        for (int j = 0; j < 4; ++j) acc[i][j] = (floatx4)0.0f;

    const int urow = tid >> 4, ucol2 = (tid & 15) * 2;   // A-stage: 2 fp32 per thread
    for (int k0 = 0; k0 < 256; k0 += 32) {
        __syncthreads();
        float2 v = *(const float2*)(u + (size_t)(m0 + urow) * 256 + k0 + ucol2);
        As32[urow * 16 + (tid & 15)] = packbf(v.x, v.y);
        #pragma unroll
        for (int t = wave; t < 32; t += 8)
            async16(W1 + (size_t)(t * 16 + r4) * 256 + k0 + c4 * 8,
                    Bs + t * 1024 + lane * 16);
        __syncthreads();
        short8 a0 = *(const short8*)((char*)As32 + rr * 64 + q * 16);
        short8 a1 = *(const short8*)((char*)As32 + (16 + rr) * 64 + q * 16);
        #pragma unroll
        for (int j = 0; j < 4; ++j) {
            short8 b = *(const short8*)(Bs + ((wave * 4 + j) * 16 + rr) * 64 + q * 16);
            acc[0][j] = __builtin_amdgcn_mfma_f32_16x16x32_bf16(a0, b, acc[0][j], 0, 0, 0);
            acc[1][j] = __builtin_amdgcn_mfma_f32_16x16x32_bf16(a1, b, acc[1][j], 0, 0, 0);
        }
    }
    __syncthreads();
    // dump Bu tile (32 x 512) into padded LDS X
    #pragma unroll
    for (int i = 0; i < 2; ++i)
        #pragma unroll
        for (int j = 0; j < 4; ++j)
            #pragma unroll
            for (int r0 = 0; r0 < 4; ++r0)
                X[(i * 16 + q * 4 + r0) * XSTRIDE + wave * 64 + j * 16 + rr] =
                    f2bs(acc[i][j][r0]);
    __syncthreads();

    // local chunk scan in LDS (threads 0..255; one channel pair each)
    if (tid < 256) {
        const int p = tid;
        const float2 lam = lam_pow(Lr[p], Li[p], expf(ls[p]));
        unsigned* xs32 = (unsigned*)(ws + OFF_XS);
        float xr = 0.0f, xi = 0.0f;
        for (int j = 0; j < LC; ++j) {
            unsigned cv = X32[j * (XSTRIDE / 2) + p];
            float br = bf2f(cv & 0xffffu), bi = bf2f(cv >> 16);
            float nr = fmaf(lam.x, xr, fmaf(-lam.y, xi, br));
            float ni = fmaf(lam.x, xi, fmaf(lam.y, xr, bi));
            xr = nr; xi = ni;
            xs32[(size_t)(m0 + j) * 256 + p] = packbf(xr, xi);
        }
        ((float2*)(ws + OFF_CEND))[bc * 256 + p] = make_float2(xr, xi);
    }
}

// ---------------- GEMM2 with inline carry fixup: out = (x_local + lam^{j+1}*carry) @ W2T^T + D*u
// BM=64, BN=128, BK=32, grid (2, 256) = 512 blocks, 4 waves as 2x2 (MT=2, NT=4).
__global__ __launch_bounds__(256, 2) void k_gemm2fix(
        const char* __restrict__ ws_c, const float* __restrict__ D,
        const float* __restrict__ u, float* __restrict__ out,
        const float* __restrict__ Lr, const float* __restrict__ Li,
        const float* __restrict__ ls) {
    __shared__ unsigned short As[64 * 32];      // 4 KB
    __shared__ unsigned short Bs[128 * 32];     // 8 KB
    __shared__ float2 carr[2][256];             // 4 KB (carries for the block's 2 chunks)
    const unsigned short* W2 = (const unsigned short*)(ws_c + OFF_W2T);
    const unsigned* xs32 = (const unsigned*)(ws_c + OFF_XS);
    const float2* pw = (const float2*)(ws_c + OFF_PW);
    const float2* cend = (const float2*)(ws_c + OFF_CEND);

    const int tid = threadIdx.x;
    const int wave = tid >> 6, lane = tid & 63;
    const int q = lane >> 4, rr = lane & 15;
    const int c4 = lane & 3, r4 = lane >> 2;
    const int wm = wave & 1, wn = wave >> 1;
    const int m0 = blockIdx.y * 64, n0 = blockIdx.x * 128;
    const int b = m0 >> 10;            // sequence index
    const int c = (m0 >> 5) & 31;      // first chunk index within sequence

    // ---- prologue: exclusive carries for chunks c and c+1 (thread = pair p) ----
    {
        const int p = tid;
        const float dt = expf(ls[p]);
        const float2 g = lam_pow(Lr[p], Li[p], dt * (float)LC);   // lambda^LC
        float sr = 0.0f, si = 0.0f;
        for (int cc = 0; cc < c; ++cc) {
            float2 e = cend[(size_t)(b * NC + cc) * 256 + p];
            float nr = fmaf(g.x, sr, fmaf(-g.y, si, e.x));
            float ni = fmaf(g.x, si, fmaf(g.y, sr, e.y));
            sr = nr; si = ni;
        }
        carr[0][p] = make_float2(sr, si);
        float2 e = cend[(size_t)(b * NC + c) * 256 + p];
        carr[1][p] = make_float2(fmaf(g.x, sr, fmaf(-g.y, si, e.x)),
                                 fmaf(g.x, si, fmaf(g.y, sr, e.y)));
    }

    floatx4 acc[2][4];
    #pragma unroll
    for (int i = 0; i < 2; ++i)
        #pragma unroll
        for (int j = 0; j < 4; ++j) acc[i][j] = (floatx4)0.0f;

    // staging mapping: thread -> (row r, pair-quad qd); 4 pairs per thread per k-step
    const int sr_ = tid & 63;             // tile row
    const int qd  = tid >> 6;             // 0..3
    const int grow = m0 + sr_;            // global row
    const int jj = (grow & (LC - 1)) + 1; // j+1
    const int half = sr_ >> 5;            // which of the 2 chunks

    for (int k0 = 0; k0 < 512; k0 += 32) {
        __syncthreads();   // also publishes carr[] on first iteration
        {
            int p0 = (k0 >> 1) + qd * 4;
            uint4 xv = *(const uint4*)(xs32 + (size_t)grow * 256 + p0);
            float4 pw01 = *(const float4*)(pw + (size_t)jj * 256 + p0);
            float4 pw23 = *(const float4*)(pw + (size_t)jj * 256 + p0 + 2);
            float4 ca01 = *(const float4*)(&carr[half][p0]);
            float4 ca23 = *(const float4*)(&carr[half][p0 + 2]);
            unsigned o0 = packbf(bf2f(xv.x & 0xffffu) + (pw01.x * ca01.x - pw01.y * ca01.y),
                                 bf2f(xv.x >> 16)     + (pw01.x * ca01.y + pw01.y * ca01.x));
            unsigned o1 = packbf(bf2f(xv.y & 0xffffu) + (pw01.z * ca01.z - pw01.w * ca01.w),
                                 bf2f(xv.y >> 16)     + (pw01.z * ca01.w + pw01.w * ca01.z));
            unsigned o2 = packbf(bf2f(xv.z & 0xffffu) + (pw23.x * ca23.x - pw23.y * ca23.y),
                                 bf2f(xv.z >> 16)     + (pw23.x * ca23.y + pw23.y * ca23.x));
            unsigned o3 = packbf(bf2f(xv.w & 0xffffu) + (pw23.z * ca23.z - pw23.w * ca23.w),
                                 bf2f(xv.w >> 16)     + (pw23.z * ca23.w + pw23.w * ca23.z));
            *(uint4*)((char*)As + sr_ * 64 + qd * 16) = make_uint4(o0, o1, o2, o3);
        }
        #pragma unroll
        for (int t = wave; t < 8; t += 4)     // B tile: 128 x 32 via async DMA
            async16(W2 + (size_t)(n0 + t * 16 + r4) * 512 + k0 + c4 * 8,
                    (char*)Bs + t * 1024 + lane * 16);
        __syncthreads();
        short8 a[2], bfrag[4];
        #pragma unroll
        for (int i = 0; i < 2; ++i)
            a[i] = *(const short8*)((const char*)As + ((wm * 2 + i) * 16 + rr) * 64 + q * 16);
        #pragma unroll
        for (int j = 0; j < 4; ++j)
            bfrag[j] = *(const short8*)((const char*)Bs + ((wn * 4 + j) * 16 + rr) * 64 + q * 16);
        #pragma unroll
        for (int i = 0; i < 2; ++i)
            #pragma unroll
            for (int j = 0; j < 4; ++j)
                acc[i][j] = __builtin_amdgcn_mfma_f32_16x16x32_bf16(a[i], bfrag[j], acc[i][j], 0, 0, 0);
    }

    #pragma unroll
    for (int i = 0; i < 2; ++i) {
        int mbase = m0 + wm * 32 + i * 16 + q * 4;
        #pragma unroll
        for (int j = 0; j < 4; ++j) {
            int col = n0 + wn * 64 + j * 16 + rr;
            #pragma unroll
            for (int r0 = 0; r0 < 4; ++r0) {
                int row = mbase + r0;
                size_t gi = (size_t)row * 256 + col;
                out[gi] = acc[i][j][r0] + D[col] * u[gi];
            }
        }
    }
}

extern "C" void kernel_launch(void* const* d_in, const int* in_sizes, int n_in,
                              void* d_out, int out_size, void* d_ws, size_t ws_size,
                              hipStream_t stream) {
    const float* u  = (const float*)d_in[0];
    const float* Lr = (const float*)d_in[1];
    const float* Li = (const float*)d_in[2];
    const float* Bm = (const float*)d_in[3];
    const float* Cm = (const float*)d_in[4];
    const float* D  = (const float*)d_in[5];
    const float* ls = (const float*)d_in[6];
    float* out = (float*)d_out;
    char* ws = (char*)d_ws;

    k_prep<<<512, 256, 0, stream>>>(Bm, Cm, Lr, Li, ls, ws);
    k_g1scan<<<NCHUNK, 512, 0, stream>>>(u, Lr, Li, ls, ws);
    k_gemm2fix<<<dim3(2, MROWS / 64), 256, 0, stream>>>(ws, D, u, out, Lr, Li, ls);
}

// Round 7
// 114.953 us; speedup vs baseline: 1.0715x; 1.0715x over previous
//
#include <hip/hip_runtime.h>
#include <hip/hip_bf16.h>
#include <math.h>

// S5 SSM layer. B_SZ=16, L=1024, H=256, P=256.
// 4 dispatches:
//   k_prep   : W1T, W2T, PW (lambda-power table)
//   k_g1scan : per-chunk GEMM1 (u@B_bar^T, BK=64) -> LDS -> local scan -> XS + CEND
//   k_carry  : exclusive chunk-carry prefix CEND -> CARR (16 blocks)
//   k_gemm2fix : GEMM2 with carry fixup folded into A-staging (BK=64) + D*u
#define BB     16
#define LSEQ   1024
#define HH     256
#define PP     256
#define MROWS  (BB*LSEQ)     // 16384
#define LC     32
#define NC     (LSEQ/LC)     // 32
#define NCHUNK (BB*NC)       // 512

// workspace byte offsets
#define OFF_W1T  0u          // [512][256] bf16: row 2p=Re(B_bar[p][.]), 2p+1=Im
#define OFF_W2T  262144u     // [256][512] bf16: row h, k=2p -> 2*C_re, 2p+1 -> -2*C_im
#define OFF_PW   524288u     // [33][256] float2: lambda_bar^t
#define OFF_CEND 655360u     // [512][256] float2 chunk-end local states
#define OFF_CARR 1703936u    // [512][256] float2 exclusive chunk carries
#define OFF_XS   2752512u    // [16384][512] bf16 x_local (col 2p=re, 2p+1=im)
// total ~19.5 MB

#define XSTRIDE 520          // bf16 elems per LDS X row in g1scan (512 + 8 pad)

typedef __attribute__((ext_vector_type(8))) short short8;
typedef __attribute__((ext_vector_type(4))) float floatx4;

__device__ __forceinline__ float bf2f(unsigned hs) {
    union { unsigned u; float f; } v; v.u = hs << 16; return v.f;
}
__device__ __forceinline__ unsigned short f2bs(float f) {
    __hip_bfloat16 h = __float2bfloat16(f);
    union { __hip_bfloat16 h; unsigned short s; } v; v.h = h; return v.s;
}
__device__ __forceinline__ unsigned packbf(float r, float i) {
    return (unsigned)f2bs(r) | ((unsigned)f2bs(i) << 16);
}
__device__ __forceinline__ void async16(const void* g, void* l) {
    __builtin_amdgcn_global_load_lds(
        (const __attribute__((address_space(1))) unsigned*)g,
        (__attribute__((address_space(3))) unsigned*)l, 16, 0, 0);
}
__device__ __forceinline__ float2 lam_pow(float lr, float li, float dtt) {
    float m = expf(lr * dtt);
    return make_float2(m * cosf(li * dtt), m * sinf(li * dtt));
}

// ---------------- prep: W1T (blocks 0..255, + PW) and W2T (blocks 256..511) ----------------
__global__ void k_prep(const float* __restrict__ Bm, const float* __restrict__ Cm,
                       const float* __restrict__ Lr, const float* __restrict__ Li,
                       const float* __restrict__ ls, char* __restrict__ ws) {
    int blk = blockIdx.x, t = threadIdx.x;
    if (blk < 256) {
        int p = blk, h = t;
        float lr = Lr[p], li = Li[p];
        float dt = expf(ls[p]);
        float2 lam = lam_pow(lr, li, dt);
        float den = lr * lr + li * li;
        float nr = lam.x - 1.0f, ni = lam.y;
        float cr = (nr * lr + ni * li) / den;       // (lam_bar-1)/Lambda
        float ci = (ni * lr - nr * li) / den;
        float br = Bm[(p * HH + h) * 2 + 0];
        float bi = Bm[(p * HH + h) * 2 + 1];
        unsigned short* w1 = (unsigned short*)(ws + OFF_W1T);
        w1[(2 * p) * 256 + h]     = f2bs(cr * br - ci * bi);
        w1[(2 * p + 1) * 256 + h] = f2bs(cr * bi + ci * br);
        if (t <= 32)   // lambda power table pw[t][p]
            ((float2*)(ws + OFF_PW))[t * 256 + p] = lam_pow(lr, li, dt * (float)t);
    } else {
        int h = blk - 256, p = t;
        float c_r = Cm[(h * PP + p) * 2 + 0];
        float c_i = Cm[(h * PP + p) * 2 + 1];
        ((unsigned*)(ws + OFF_W2T))[h * 256 + p] = packbf(2.0f * c_r, -2.0f * c_i);
    }
}

// ---------------- fused GEMM1 + local chunk scan (512 threads, BK=64 two-panel) ----------------
// One block per chunk: rows m0..m0+31, N=512, K=256 in 4 iters of 64.
__global__ __launch_bounds__(512, 2) void k_g1scan(
        const float* __restrict__ u, const float* __restrict__ Lr,
        const float* __restrict__ Li, const float* __restrict__ ls,
        char* __restrict__ ws) {
    __shared__ char smem[4096 + 65536];  // As[2][32][32]bf16 | Bs[2][512][32]bf16 ; X 32x520 unions at 0
    char* Asb = smem;
    char* Bsb = smem + 4096;
    unsigned short* X = (unsigned short*)smem;
    unsigned* X32 = (unsigned*)smem;
    const unsigned short* W1 = (const unsigned short*)(ws + OFF_W1T);
    const int tid = threadIdx.x, bc = blockIdx.x;
    const int wave = tid >> 6, lane = tid & 63;
    const int q = lane >> 4, rr = lane & 15;
    const int c4 = lane & 3, r4 = lane >> 2;
    const int m0 = bc * LC;

    floatx4 acc[2][4];
    #pragma unroll
    for (int i = 0; i < 2; ++i)
        #pragma unroll
        for (int j = 0; j < 4; ++j) acc[i][j] = (floatx4)0.0f;

    const int arow = tid >> 4, acol4 = (tid & 15) * 4;   // A-stage: one float4/thread
    const int apan = acol4 >> 5, acin = acol4 & 31;
    for (int k0 = 0; k0 < 256; k0 += 64) {
        __syncthreads();
        float4 v = *(const float4*)(u + (size_t)(m0 + arow) * 256 + k0 + acol4);
        *(uint2*)(Asb + apan * 2048 + arow * 64 + acin * 2) =
            make_uint2(packbf(v.x, v.y), packbf(v.z, v.w));
        #pragma unroll
        for (int t = 0; t < 8; ++t) {                    // Bs: 512 rows x 2 panels
            int idx = t * 8 + wave;
            int pan = idx & 1, rowg = idx >> 1;
            int row = rowg * 16 + r4;
            async16(W1 + (size_t)row * 256 + k0 + pan * 32 + c4 * 8,
                    Bsb + pan * 32768 + row * 64 + c4 * 16);
        }
        __syncthreads();
        #pragma unroll
        for (int ks = 0; ks < 2; ++ks) {
            short8 a0 = *(const short8*)(Asb + ks * 2048 + rr * 64 + q * 16);
            short8 a1 = *(const short8*)(Asb + ks * 2048 + (16 + rr) * 64 + q * 16);
            #pragma unroll
            for (int j = 0; j < 4; ++j) {
                short8 b = *(const short8*)(Bsb + ks * 32768 +
                                            ((wave * 4 + j) * 16 + rr) * 64 + q * 16);
                acc[0][j] = __builtin_amdgcn_mfma_f32_16x16x32_bf16(a0, b, acc[0][j], 0, 0, 0);
                acc[1][j] = __builtin_amdgcn_mfma_f32_16x16x32_bf16(a1, b, acc[1][j], 0, 0, 0);
            }
        }
    }
    __syncthreads();
    // dump Bu tile (32 x 512) into padded LDS X
    #pragma unroll
    for (int i = 0; i < 2; ++i)
        #pragma unroll
        for (int j = 0; j < 4; ++j)
            #pragma unroll
            for (int r0 = 0; r0 < 4; ++r0)
                X[(i * 16 + q * 4 + r0) * XSTRIDE + wave * 64 + j * 16 + rr] =
                    f2bs(acc[i][j][r0]);
    __syncthreads();

    // local chunk scan in LDS (threads 0..255; one channel pair each)
    if (tid < 256) {
        const int p = tid;
        const float2 lam = lam_pow(Lr[p], Li[p], expf(ls[p]));
        unsigned* xs32 = (unsigned*)(ws + OFF_XS);
        float xr = 0.0f, xi = 0.0f;
        for (int j = 0; j < LC; ++j) {
            unsigned cv = X32[j * (XSTRIDE / 2) + p];
            float br = bf2f(cv & 0xffffu), bi = bf2f(cv >> 16);
            float nr = fmaf(lam.x, xr, fmaf(-lam.y, xi, br));
            float ni = fmaf(lam.x, xi, fmaf(lam.y, xr, bi));
            xr = nr; xi = ni;
            xs32[(size_t)(m0 + j) * 256 + p] = packbf(xr, xi);
        }
        ((float2*)(ws + OFF_CEND))[bc * 256 + p] = make_float2(xr, xi);
    }
}

// ---------------- carry: exclusive prefix of chunk carries (16 blocks) ----------------
__global__ void k_carry(const float* __restrict__ Lr, const float* __restrict__ Li,
                        const float* __restrict__ ls, char* __restrict__ ws) {
    int p = threadIdx.x, b = blockIdx.x;
    float dt = expf(ls[p]);
    float2 g = lam_pow(Lr[p], Li[p], dt * (float)LC);   // lambda^LC
    const float2* cend = (const float2*)(ws + OFF_CEND);
    float2* carr = (float2*)(ws + OFF_CARR);
    float sr = 0.0f, si = 0.0f;
    for (int c = 0; c < NC; ++c) {
        size_t off = (size_t)(b * NC + c) * 256 + p;
        carr[off] = make_float2(sr, si);
        float2 e = cend[off];
        float nr = fmaf(g.x, sr, fmaf(-g.y, si, e.x));
        float ni = fmaf(g.x, si, fmaf(g.y, sr, e.y));
        sr = nr; si = ni;
    }
}

// ---------------- GEMM2 with inline carry fixup (BK=64 two-panel) ----------------
// out = (x_local + lam^{j+1}*carry) @ W2T^T + D*u. BM=64, BN=128, grid (2,256).
__global__ __launch_bounds__(256, 4) void k_gemm2fix(
        const char* __restrict__ ws_c, const float* __restrict__ D,
        const float* __restrict__ u, float* __restrict__ out) {
    __shared__ char Asb[8192];          // [2][64][32] bf16
    __shared__ char Bsb[16384];         // [2][128][32] bf16
    __shared__ float2 carrs[2][256];    // this block's 2 chunk carries
    const unsigned short* W2 = (const unsigned short*)(ws_c + OFF_W2T);
    const unsigned* xs32 = (const unsigned*)(ws_c + OFF_XS);
    const float2* pw = (const float2*)(ws_c + OFF_PW);
    const float2* carr = (const float2*)(ws_c + OFF_CARR);

    const int tid = threadIdx.x;
    const int wave = tid >> 6, lane = tid & 63;
    const int q = lane >> 4, rr = lane & 15;
    const int c4 = lane & 3, r4 = lane >> 2;
    const int wm = wave & 1, wn = wave >> 1;
    const int m0 = blockIdx.y * 64, n0 = blockIdx.x * 128;

    {   // stage this block's carries (chunks m0/32 and m0/32+1)
        int cbase = m0 >> 5;
        carrs[0][tid] = carr[(size_t)cbase * 256 + tid];
        carrs[1][tid] = carr[(size_t)(cbase + 1) * 256 + tid];
    }

    floatx4 acc[2][4];
    #pragma unroll
    for (int i = 0; i < 2; ++i)
        #pragma unroll
        for (int j = 0; j < 4; ++j) acc[i][j] = (floatx4)0.0f;

    const int row = tid >> 2, qd = tid & 3;    // staging: 8 pairs/thread/iter
    const int grow = m0 + row;
    const int jj = (grow & (LC - 1)) + 1;
    const int half = row >> 5;

    for (int k0 = 0; k0 < 512; k0 += 64) {
        __syncthreads();   // publishes carrs on first iteration
        {
            int p0 = (k0 >> 1) + qd * 8;
            uint4 xa = *(const uint4*)(xs32 + (size_t)grow * 256 + p0);
            uint4 xb = *(const uint4*)(xs32 + (size_t)grow * 256 + p0 + 4);
            unsigned xv[8] = {xa.x, xa.y, xa.z, xa.w, xb.x, xb.y, xb.z, xb.w};
            const float2* pwp = pw + (size_t)jj * 256 + p0;
            const float2* cap = &carrs[half][p0];
            unsigned o[8];
            #pragma unroll
            for (int e = 0; e < 8; ++e) {
                float2 pwv = pwp[e];
                float2 cav = cap[e];
                float fr = pwv.x * cav.x - pwv.y * cav.y;
                float fi = pwv.x * cav.y + pwv.y * cav.x;
                o[e] = packbf(bf2f(xv[e] & 0xffffu) + fr, bf2f(xv[e] >> 16) + fi);
            }
            char* dst = Asb + (qd >> 1) * 4096 + row * 64 + (qd & 1) * 32;
            *(uint4*)dst        = make_uint4(o[0], o[1], o[2], o[3]);
            *(uint4*)(dst + 16) = make_uint4(o[4], o[5], o[6], o[7]);
        }
        #pragma unroll
        for (int t = 0; t < 4; ++t) {          // Bs: 128 rows x 2 panels
            int idx = t * 4 + wave;
            int pan = idx & 1, rowg = idx >> 1;
            int rw = rowg * 16 + r4;
            async16(W2 + (size_t)(n0 + rw) * 512 + k0 + pan * 32 + c4 * 8,
                    Bsb + pan * 8192 + rw * 64 + c4 * 16);
        }
        __syncthreads();
        #pragma unroll
        for (int ks = 0; ks < 2; ++ks) {
            short8 a[2], bfr[4];
            #pragma unroll
            for (int i = 0; i < 2; ++i)
                a[i] = *(const short8*)(Asb + ks * 4096 +
                                        (wm * 32 + i * 16 + rr) * 64 + q * 16);
            #pragma unroll
            for (int j = 0; j < 4; ++j)
                bfr[j] = *(const short8*)(Bsb + ks * 8192 +
                                          ((wn * 64 + j * 16 + rr)) * 64 + q * 16);
            #pragma unroll
            for (int i = 0; i < 2; ++i)
                #pragma unroll
                for (int j = 0; j < 4; ++j)
                    acc[i][j] = __builtin_amdgcn_mfma_f32_16x16x32_bf16(a[i], bfr[j], acc[i][j], 0, 0, 0);
        }
    }

    #pragma unroll
    for (int i = 0; i < 2; ++i) {
        int mbase = m0 + wm * 32 + i * 16 + q * 4;
        #pragma unroll
        for (int j = 0; j < 4; ++j) {
            int col = n0 + wn * 64 + j * 16 + rr;
            #pragma unroll
            for (int r0 = 0; r0 < 4; ++r0) {
                int rw = mbase + r0;
                size_t gi = (size_t)rw * 256 + col;
                out[gi] = acc[i][j][r0] + D[col] * u[gi];
            }
        }
    }
}

extern "C" void kernel_launch(void* const* d_in, const int* in_sizes, int n_in,
                              void* d_out, int out_size, void* d_ws, size_t ws_size,
                              hipStream_t stream) {
    const float* u  = (const float*)d_in[0];
    const float* Lr = (const float*)d_in[1];
    const float* Li = (const float*)d_in[2];
    const float* Bm = (const float*)d_in[3];
    const float* Cm = (const float*)d_in[4];
    const float* D  = (const float*)d_in[5];
    const float* ls = (const float*)d_in[6];
    float* out = (float*)d_out;
    char* ws = (char*)d_ws;

    k_prep<<<512, 256, 0, stream>>>(Bm, Cm, Lr, Li, ls, ws);
    k_g1scan<<<NCHUNK, 512, 0, stream>>>(u, Lr, Li, ls, ws);
    k_carry<<<BB, 256, 0, stream>>>(Lr, Li, ls, ws);
    k_gemm2fix<<<dim3(2, MROWS / 64), 256, 0, stream>>>(ws, D, u, out);
}